// Round 5
// baseline (2347.764 us; speedup 1.0000x reference)
//
#include <hip/hip_runtime.h>

#define EPS 1e-5f

typedef __attribute__((ext_vector_type(8))) short s8v;   // 8 x bf16 bits
typedef __attribute__((ext_vector_type(4))) float f4v;   // MFMA accumulator

__device__ __forceinline__ unsigned short f2b(float x) {
  unsigned int u = __float_as_uint(x);
  u += 0x7FFFu + ((u >> 16) & 1u);
  return (unsigned short)(u >> 16);
}
__device__ __forceinline__ float b2f(unsigned short b) {
  return __uint_as_float(((unsigned int)b) << 16);
}

// ---------------------------------------------------------------------------
// Split-K GEMM with fused semaphore reduction.
//   A: 256 x K bf16 (lda padded to >= K rounded up to 32, zero pads)
//   B: N x K f32 row-major
//   Tile 256x32, BK=32, 4 waves. bid = ky*NTP + nt.
//   Partials tile-major: P[(ky*NT+nt)*8192 + row*32 + lcol].
//   Last block per nt (semaphore) reduces + epilogue.
//   HOST INVARIANT: kchunk % 32 == 0 (otherwise interior chunks would stage
//   a full 32-wide slab past kend and double-count k-columns — round-4 bug).
// ---------------------------------------------------------------------------
template<bool BN, bool RES, bool WRD, bool WRT, bool F32OUT>
__global__ __launch_bounds__(256)
void gemm_fused(const unsigned short* __restrict__ A, int lda,
                const float* __restrict__ B, int ldb,
                float* __restrict__ P, unsigned int* __restrict__ sem,
                int NT, int NTP, int N, int K, int kchunk, int KS,
                const float* __restrict__ bias,
                const float* __restrict__ g, const float* __restrict__ bb,
                const float* __restrict__ rm, const float* __restrict__ rv,
                float* __restrict__ dR, int lddr,
                unsigned short* __restrict__ Cb, int ldc,
                unsigned short* __restrict__ Ct, float* __restrict__ Cf)
{
  __shared__ unsigned short As[256 * 40];
  __shared__ unsigned short Bs[32 * 40];
  __shared__ unsigned int s_old;
  const int bid = (int)blockIdx.x;
  const int ky = bid / NTP, nt = bid % NTP;
  if (nt >= NT) return;
  const int n0 = nt << 5;
  const int t = threadIdx.x, lane = t & 63, w = t >> 6;
  const int lr = lane & 15, lk = lane >> 4;

  const int kstart = ky * kchunk;
  const int kend = min(K, kstart + kchunk);
  const int nfull = (kend - kstart) >> 5;
  const int rem = (kend - kstart) & 31;

  const int ar0 = t >> 2, akc = t & 3;
  const int br0 = t >> 4, bkh = t & 15;

  f4v acc[4][2] = {};
  s8v a_cur[4]; float2 b_cur[2];
  s8v a_nxt[4]; float2 b_nxt[2];

  auto loadA = [&](s8v* dst, int kb) {
    #pragma unroll
    for (int j = 0; j < 4; ++j)
      dst[j] = *(const s8v*)(A + (size_t)(ar0 + j * 64) * lda + kb + akc * 8);
  };
  auto loadB = [&](float2* dst, int kb) {
    #pragma unroll
    for (int j = 0; j < 2; ++j) {
      const int row = n0 + br0 + j * 16;
      if (row < N) dst[j] = *(const float2*)(B + (size_t)row * ldb + kb + bkh * 2);
      else { dst[j].x = 0.f; dst[j].y = 0.f; }
    }
  };
  auto stage = [&](const s8v* av, const float2* bv) {
    #pragma unroll
    for (int j = 0; j < 4; ++j)
      *(s8v*)(As + (ar0 + j * 64) * 40 + akc * 8) = av[j];
    #pragma unroll
    for (int j = 0; j < 2; ++j) {
      unsigned int pk = (unsigned int)f2b(bv[j].x) | ((unsigned int)f2b(bv[j].y) << 16);
      *(unsigned int*)(Bs + (br0 + j * 16) * 40 + bkh * 2) = pk;
    }
  };
  auto domfma = [&]() {
    s8v af[4], bf[2];
    #pragma unroll
    for (int fm = 0; fm < 4; ++fm)
      af[fm] = *(const s8v*)(As + (w * 64 + fm * 16 + lr) * 40 + lk * 8);
    #pragma unroll
    for (int fn = 0; fn < 2; ++fn)
      bf[fn] = *(const s8v*)(Bs + (fn * 16 + lr) * 40 + lk * 8);
    #pragma unroll
    for (int fm = 0; fm < 4; ++fm)
      #pragma unroll
      for (int fn = 0; fn < 2; ++fn)
        acc[fm][fn] = __builtin_amdgcn_mfma_f32_16x16x32_bf16(af[fm], bf[fn], acc[fm][fn], 0, 0, 0);
  };

  int kb = kstart;
  if (nfull > 0) {
    loadA(a_cur, kb); loadB(b_cur, kb);
    for (int s = 0; s < nfull; ++s) {
      stage(a_cur, b_cur);
      __syncthreads();
      const bool more = (s + 1 < nfull);
      if (more) { loadA(a_nxt, kb + 32); loadB(b_nxt, kb + 32); }
      domfma();
      __syncthreads();
      if (more) {
        #pragma unroll
        for (int j = 0; j < 4; ++j) a_cur[j] = a_nxt[j];
        b_cur[0] = b_nxt[0]; b_cur[1] = b_nxt[1];
        kb += 32;
      }
    }
    kb += 32;
  }
  if (rem) {
    // Only reachable in the LAST chunk (kchunk % 32 == 0) -> kend == K.
    // A pads (cols K..lda) are zero by construction; B guarded by kend.
    loadA(a_cur, kb);
    #pragma unroll
    for (int j = 0; j < 2; ++j) {
      const int row = n0 + br0 + j * 16;
      const int kk = kb + bkh * 2;
      float e0 = (row < N && kk < kend) ? B[(size_t)row * ldb + kk] : 0.f;
      float e1 = (row < N && kk + 1 < kend) ? B[(size_t)row * ldb + kk + 1] : 0.f;
      b_cur[j].x = e0; b_cur[j].y = e1;
    }
    stage(a_cur, b_cur);
    __syncthreads();
    domfma();
    __syncthreads();
  }

  // Write partial tile (tile-major, 32 KB)
  float* Pk = P + ((size_t)ky * NT + nt) * 8192;
  #pragma unroll
  for (int fm = 0; fm < 4; ++fm)
    #pragma unroll
    for (int fn = 0; fn < 2; ++fn) {
      const int lcol = fn * 16 + lr;
      #pragma unroll
      for (int j = 0; j < 4; ++j) {
        const int row = w * 64 + fm * 16 + lk * 4 + j;
        Pk[row * 32 + lcol] = acc[fm][fn][j];
      }
    }

  // Semaphore: last block per nt reduces (release/acquire, device scope)
  __threadfence();
  __syncthreads();
  if (t == 0)
    s_old = __hip_atomic_fetch_add(&sem[nt], 1u, __ATOMIC_ACQ_REL,
                                   __HIP_MEMORY_SCOPE_AGENT);
  __syncthreads();
  if (s_old != (unsigned int)(KS - 1)) return;
  __threadfence();

  const float* Pt = P + (size_t)nt * 8192;
  #pragma unroll
  for (int q = 0; q < 8; ++q) {
    const int i4 = t + 256 * q;       // 0..2047 float4 groups
    const int row = i4 >> 3;
    const int cb = (i4 & 7) * 4;
    float vv[4] = {0.f, 0.f, 0.f, 0.f};
    for (int kk = 0; kk < KS; ++kk) {
      const float4 pv = *(const float4*)(Pt + (size_t)kk * NT * 8192 + row * 32 + cb);
      vv[0] += pv.x; vv[1] += pv.y; vv[2] += pv.z; vv[3] += pv.w;
    }
    #pragma unroll
    for (int e = 0; e < 4; ++e) {
      const int col = n0 + cb + e;
      if (col >= N) {
        if (!WRT && !F32OUT) Cb[(size_t)row * ldc + col] = 0;
        continue;
      }
      float v = vv[e] + bias[col];
      if (BN) { const float s = g[col] * rsqrtf(rv[col] + EPS); v = (v - rm[col]) * s + bb[col]; }
      v = fmaxf(v, 0.f);
      if (RES) v += dR[(size_t)row * lddr + col];
      if (WRD) dR[(size_t)row * lddr + col] = v;
      if (F32OUT) Cf[(size_t)row * N + col] = v;
      else if (WRT) Ct[(size_t)col * 256 + row] = f2b(v);
      else Cb[(size_t)row * ldc + col] = f2b(v);
    }
  }
  if (t == 0)
    __hip_atomic_store(&sem[nt], 0u, __ATOMIC_RELAXED, __HIP_MEMORY_SCOPE_AGENT);
}

// ---------------------------------------------------------------------------
// Prep: pack x-geno to bf16, pack env rows, zero h5b pads + semaphores.
// ---------------------------------------------------------------------------
__global__ __launch_bounds__(256)
void prep_k(const float* __restrict__ x, unsigned short* __restrict__ xg,
            unsigned short* __restrict__ envb, unsigned short* __restrict__ h5b,
            unsigned int* __restrict__ sem)
{
  const int bid = (int)blockIdx.x, t = threadIdx.x;
  if (bid < 16384) {
    const int idx = bid * 256 + t;
    const int r = idx >> 14, c = idx & 16383;
    xg[idx] = f2b(x[(size_t)r * 16437 + c]);
  } else if (bid < 16456) {
    const int idx = (bid - 16384) * 256 + t;
    const int b = idx / 72, c = idx % 72;
    envb[idx] = (c < 53) ? f2b(x[(size_t)b * 16437 + 16384 + c]) : (unsigned short)0;
  } else {
    if (t < 128) sem[t] = 0;
    for (int z = t; z < 256 * 14; z += 256) {
      const int b = z / 14, j = z % 14;
      h5b[(size_t)b * 13344 + 13330 + j] = 0;
    }
  }
}

// ---------------------------------------------------------------------------
// Fused head: per unit i, 4 chained 256x64x64 GEMMs in LDS/regs.
// ---------------------------------------------------------------------------
__global__ __launch_bounds__(256, 2)
void fused_head(const unsigned short* __restrict__ envb,
                const unsigned short* __restrict__ htr,
                const float* __restrict__ Wlin, const float* __restrict__ blin,
                const float* __restrict__ W13, const float* __restrict__ b13,
                const float* __restrict__ W14, const float* __restrict__ b14,
                const float* __restrict__ W15, const float* __restrict__ b15,
                const float* __restrict__ bn3g, const float* __restrict__ bn3b,
                const float* __restrict__ bn3rm, const float* __restrict__ bn3rv,
                unsigned short* __restrict__ h5b)
{
  __shared__ unsigned short act[256 * 72];
  __shared__ unsigned short Wl[64 * 72];
  __shared__ unsigned short Wa[64 * 72];
  __shared__ unsigned short Wb[16 * 72];
  const int i = (int)blockIdx.x;
  const int t = threadIdx.x, lane = t & 63, w = t >> 6;
  const int lr = lane & 15, lk = lane >> 4;
  const int R = 2666;

  #pragma unroll
  for (int c8 = 0; c8 < 9; ++c8)
    *(s8v*)(act + t * 72 + c8 * 8) = *(const s8v*)(envb + t * 72 + c8 * 8);
  act[t * 72 + 53] = htr[(size_t)i * 256 + t];

  const float* wli = Wlin + (size_t)i * 2916;
  for (int idx = t; idx < 64 * 72; idx += 256) {
    const int r = idx / 72, f = idx % 72;
    Wl[idx] = (r < 54 && f < 54) ? f2b(wli[r * 54 + f]) : (unsigned short)0;
    Wa[idx] = (r < 54 && f < 54) ? f2b(W13[r * 54 + f]) : (unsigned short)0;
  }
  for (int idx = t; idx < 16 * 72; idx += 256) {
    const int r = idx / 72, f = idx % 72;
    Wb[idx] = (r < 5 && f < 54) ? f2b(W15[r * 54 + f]) : (unsigned short)0;
  }
  const float s0 = bn3g[i] * rsqrtf(bn3rv[i] + EPS), m0 = bn3rm[i], c0 = bn3b[i];
  const float s1 = bn3g[R+i] * rsqrtf(bn3rv[R+i] + EPS), m1 = bn3rm[R+i], c1 = bn3b[R+i];
  const float s2 = bn3g[2*R+i] * rsqrtf(bn3rv[2*R+i] + EPS), m2 = bn3rm[2*R+i], c2 = bn3b[2*R+i];
  __syncthreads();

  const int abase = (w * 64 + lr) * 72 + lk * 8;
  f4v acc[4][4];

  auto zacc = [&]() {
    #pragma unroll
    for (int a = 0; a < 4; ++a)
      #pragma unroll
      for (int b = 0; b < 4; ++b) acc[a][b] = f4v{0.f, 0.f, 0.f, 0.f};
  };
  auto gemm4 = [&](const unsigned short* B) {
    s8v af[2][4];
    #pragma unroll
    for (int ks = 0; ks < 2; ++ks)
      #pragma unroll
      for (int fm = 0; fm < 4; ++fm)
        af[ks][fm] = *(const s8v*)(act + abase + fm * 16 * 72 + ks * 32);
    #pragma unroll
    for (int fn = 0; fn < 4; ++fn) {
      s8v b0 = *(const s8v*)(B + (fn * 16 + lr) * 72 + lk * 8);
      s8v b1 = *(const s8v*)(B + (fn * 16 + lr) * 72 + 32 + lk * 8);
      #pragma unroll
      for (int fm = 0; fm < 4; ++fm) {
        acc[fm][fn] = __builtin_amdgcn_mfma_f32_16x16x32_bf16(af[0][fm], b0, acc[fm][fn], 0, 0, 0);
        acc[fm][fn] = __builtin_amdgcn_mfma_f32_16x16x32_bf16(af[1][fm], b1, acc[fm][fn], 0, 0, 0);
      }
    }
  };
  auto epi_bn = [&](const float* bias, float s, float m, float c) {
    #pragma unroll
    for (int fn = 0; fn < 4; ++fn) {
      const int o = fn * 16 + lr;
      const float bo = (o < 54) ? bias[o] : 0.f;
      #pragma unroll
      for (int fm = 0; fm < 4; ++fm)
        #pragma unroll
        for (int j = 0; j < 4; ++j) {
          const int row = w * 64 + fm * 16 + lk * 4 + j;
          float v = acc[fm][fn][j] + bo;
          v = (v - m) * s + c;
          v = fmaxf(v, 0.f);
          act[row * 72 + o] = (o < 54) ? f2b(v) : (unsigned short)0;
        }
    }
  };

  zacc(); gemm4(Wl);
  #pragma unroll
  for (int fn = 0; fn < 4; ++fn) {
    const int o = fn * 16 + lr;
    const float bl = (o < 54) ? blin[(size_t)i * 54 + o] : 0.f;
    #pragma unroll
    for (int fm = 0; fm < 4; ++fm)
      #pragma unroll
      for (int j = 0; j < 4; ++j) {
        const int row = w * 64 + fm * 16 + lk * 4 + j;
        float v = acc[fm][fn][j] + bl;
        act[row * 72 + o] = (o < 54) ? f2b(v) : (unsigned short)0;
      }
  }
  __syncthreads();
  for (int idx = t; idx < 64 * 72; idx += 256) {
    const int r = idx / 72, f = idx % 72;
    Wl[idx] = (r < 54 && f < 54) ? f2b(W14[r * 54 + f]) : (unsigned short)0;
  }
  zacc(); gemm4(Wa); epi_bn(b13, s0, m0, c0);
  __syncthreads();
  zacc(); gemm4(Wl); epi_bn(b14, s1, m1, c1);
  f4v a4[4] = {};
  {
    s8v af[2][4];
    #pragma unroll
    for (int ks = 0; ks < 2; ++ks)
      #pragma unroll
      for (int fm = 0; fm < 4; ++fm)
        af[ks][fm] = *(const s8v*)(act + abase + fm * 16 * 72 + ks * 32);
    s8v b0 = *(const s8v*)(Wb + lr * 72 + lk * 8);
    s8v b1 = *(const s8v*)(Wb + lr * 72 + 32 + lk * 8);
    #pragma unroll
    for (int fm = 0; fm < 4; ++fm) {
      a4[fm] = __builtin_amdgcn_mfma_f32_16x16x32_bf16(af[0][fm], b0, a4[fm], 0, 0, 0);
      a4[fm] = __builtin_amdgcn_mfma_f32_16x16x32_bf16(af[1][fm], b1, a4[fm], 0, 0, 0);
    }
  }
  if (lr < 5) {
    const float b5 = b15[lr];
    #pragma unroll
    for (int fm = 0; fm < 4; ++fm)
      #pragma unroll
      for (int j = 0; j < 4; ++j) {
        const int row = w * 64 + fm * 16 + lk * 4 + j;
        float v = a4[fm][j] + b5;
        v = (v - m2) * s2 + c2;
        v = fmaxf(v, 0.f);
        h5b[(size_t)row * 13344 + (size_t)i * 5 + lr] = f2b(v);
      }
  }
}

extern "C" void kernel_launch(void* const* d_in, const int* in_sizes, int n_in,
                              void* d_out, int out_size, void* d_ws, size_t ws_size,
                              hipStream_t stream)
{
  const float* x    = (const float*)d_in[0];
  const float* W1   = (const float*)d_in[1];
  const float* b1   = (const float*)d_in[2];
  const float* Wmid = (const float*)d_in[3];
  const float* bmid = (const float*)d_in[4];
  const float* bng  = (const float*)d_in[5];
  const float* bnb  = (const float*)d_in[6];
  const float* bnrm = (const float*)d_in[7];
  const float* bnrv = (const float*)d_in[8];
  const float* Wlin = (const float*)d_in[9];
  const float* blin = (const float*)d_in[10];
  const float* W13  = (const float*)d_in[11];
  const float* b13  = (const float*)d_in[12];
  const float* W14  = (const float*)d_in[13];
  const float* b14  = (const float*)d_in[14];
  const float* W15  = (const float*)d_in[15];
  const float* b15  = (const float*)d_in[16];
  const float* bn3g = (const float*)d_in[17];
  const float* bn3b = (const float*)d_in[18];
  const float* bn3rm= (const float*)d_in[19];
  const float* bn3rv= (const float*)d_in[20];
  const float* W16  = (const float*)d_in[21];
  const float* b16  = (const float*)d_in[22];
  const float* W17  = (const float*)d_in[23];
  const float* b17  = (const float*)d_in[24];
  const float* W18  = (const float*)d_in[25];
  const float* b18  = (const float*)d_in[26];

  const int R = 2666;
  char* p = (char*)d_ws;
  unsigned short* xg  = (unsigned short*)p; p += (size_t)256 * 16384 * 2;
  unsigned short* hA  = (unsigned short*)p; p += (size_t)256 * 2688 * 2;
  unsigned short* hB  = (unsigned short*)p; p += (size_t)256 * 2688 * 2;
  float*          dR  = (float*)p;          p += (size_t)256 * 2688 * 4;
  unsigned short* h5b = (unsigned short*)p; p += (size_t)256 * 13344 * 2;
  unsigned short* h6b = (unsigned short*)p; p += (size_t)256 * 768 * 2;
  unsigned short* h7b = (unsigned short*)p; p += (size_t)256 * 768 * 2;
  unsigned short* envb= (unsigned short*)p; p += (size_t)256 * 72 * 2;
  unsigned short* htr = (unsigned short*)p; p += (size_t)2666 * 256 * 2;
  unsigned int*   sem = (unsigned int*)p;   p += 256 * 4;
  float* P = (float*)p;   // split-K partials, tile-major, <= 22.1 MB

  dim3 TB(256);

  prep_k<<<dim3(16457), TB, 0, stream>>>(x, xg, envb, h5b, sem);

  // L1: K=16384, NT=84, NTP=88, KS=8, kchunk=2048 (mult of 32) -> hA (+dR)
  gemm_fused<true, false, true, false, false><<<dim3(88 * 8), TB, 0, stream>>>(
      xg, 16384, W1, 16384, P, sem, 84, 88, R, 16384, 2048, 8,
      b1, bng, bnb, bnrm, bnrv, dR, 2688, hA, 2688, nullptr, nullptr);

  // mids: K=2666, NT=84, NTP=88, KS=7, kchunk=384 (mult of 32)
  unsigned short* cur = hA; unsigned short* nxt = hB;
  for (int k = 0; k < 11; ++k) {
    const float* bw = Wmid + (size_t)k * R * R;
    const float* bs = bmid + (size_t)k * R;
    const int L = k + 1;
    if (k == 10)
      gemm_fused<true, false, false, true, false><<<dim3(88 * 7), TB, 0, stream>>>(
          cur, 2688, bw, R, P, sem, 84, 88, R, R, 384, 7,
          bs, bng + (size_t)L * R, bnb + (size_t)L * R, bnrm + (size_t)L * R, bnrv + (size_t)L * R,
          dR, 2688, nxt, 2688, htr, nullptr);
    else if ((k & 1) == 0)
      gemm_fused<true, false, false, false, false><<<dim3(88 * 7), TB, 0, stream>>>(
          cur, 2688, bw, R, P, sem, 84, 88, R, R, 384, 7,
          bs, bng + (size_t)L * R, bnb + (size_t)L * R, bnrm + (size_t)L * R, bnrv + (size_t)L * R,
          dR, 2688, nxt, 2688, nullptr, nullptr);
    else
      gemm_fused<true, true, true, false, false><<<dim3(88 * 7), TB, 0, stream>>>(
          cur, 2688, bw, R, P, sem, 84, 88, R, R, 384, 7,
          bs, bng + (size_t)L * R, bnb + (size_t)L * R, bnrm + (size_t)L * R, bnrv + (size_t)L * R,
          dR, 2688, nxt, 2688, nullptr, nullptr);
    unsigned short* tmp = cur; cur = nxt; nxt = tmp;
  }

  // Fused d3 -> W13 -> W14 -> W15 chain
  fused_head<<<dim3(2666), TB, 0, stream>>>(
      envb, htr, Wlin, blin, W13, b13, W14, b14, W15, b15,
      bn3g, bn3b, bn3rm, bn3rv, h5b);

  // W16: K=13330, NT=24, KS=16, kchunk=864 (27*32; FIX: was 834 -> interior-chunk
  // double-count). Last chunk: 12960..13330, rem=18, A pads zero up to 13344.
  gemm_fused<false, false, false, false, false><<<dim3(24 * 16), TB, 0, stream>>>(
      h5b, 13344, W16, 13330, P, sem, 24, 24, 750, 13330, 864, 16,
      b16, nullptr, nullptr, nullptr, nullptr, nullptr, 0, h6b, 768, nullptr, nullptr);

  // W17: K=750, KS=8, kchunk=96 (mult of 32) -> h7b
  gemm_fused<false, false, false, false, false><<<dim3(24 * 8), TB, 0, stream>>>(
      h6b, 768, W17, 750, P, sem, 24, 24, 750, 750, 96, 8,
      b17, nullptr, nullptr, nullptr, nullptr, nullptr, 0, h7b, 768, nullptr, nullptr);

  // W18 -> f32 d_out
  gemm_fused<false, false, false, false, true><<<dim3(24 * 8), TB, 0, stream>>>(
      h7b, 768, W18, 750, P, sem, 24, 24, 750, 750, 96, 8,
      b18, nullptr, nullptr, nullptr, nullptr, nullptr, 0, nullptr, 768, nullptr, (float*)d_out);
}

// Round 6
// 804.735 us; speedup vs baseline: 2.9174x; 2.9174x over previous
//
#include <hip/hip_runtime.h>

#define EPS 1e-5f

typedef __attribute__((ext_vector_type(8))) short s8v;   // 8 x bf16 bits
typedef __attribute__((ext_vector_type(4))) float f4v;   // MFMA accumulator

__device__ __forceinline__ unsigned short f2b(float x) {
  unsigned int u = __float_as_uint(x);
  u += 0x7FFFu + ((u >> 16) & 1u);
  return (unsigned short)(u >> 16);
}
__device__ __forceinline__ float b2f(unsigned short b) {
  return __uint_as_float(((unsigned int)b) << 16);
}

// ---------------------------------------------------------------------------
// Split-K GEMM, partials only (NO device fences — kernel boundary is the sync).
//   A: 256 x K bf16 (lda padded to mult of 32, zero pads)
//   B: N x K f32 row-major
//   Tile 256x32, BK=32, 4 waves. bid: ky = bid % KS, nt = bid / KS.
//   Partials tile-major: P[(ky*NT + nt)*8192 + row*32 + lcol]  (32 KB/tile).
//   HOST INVARIANT: kchunk % 32 == 0 (round-4 lesson: otherwise interior
//   chunks stage past kend and double-count k-columns).
// ---------------------------------------------------------------------------
__global__ __launch_bounds__(256)
void gemm_splitk(const unsigned short* __restrict__ A, int lda,
                 const float* __restrict__ B, int ldb,
                 float* __restrict__ P, int NT, int N, int K, int kchunk, int KS)
{
  __shared__ unsigned short As[256 * 40];
  __shared__ unsigned short Bs[32 * 40];
  const int bid = (int)blockIdx.x;
  const int ky = bid % KS, nt = bid / KS;
  const int n0 = nt << 5;
  const int t = threadIdx.x, lane = t & 63, w = t >> 6;
  const int lr = lane & 15, lk = lane >> 4;

  const int kstart = ky * kchunk;
  const int kend = min(K, kstart + kchunk);
  const int nfull = (kend - kstart) >> 5;
  const int rem = (kend - kstart) & 31;

  const int ar0 = t >> 2, akc = t & 3;   // A: rows ar0 + j*64, 8-bf16 chunk akc
  const int br0 = t >> 3, bq = t & 7;    // B: one row/thread, 4-col quad bq

  f4v acc[4][2] = {};
  s8v a_cur[4]; float2 b_cur[2];
  s8v a_nxt[4]; float2 b_nxt[2];

  auto loadA = [&](s8v* dst, int kb) {
    #pragma unroll
    for (int j = 0; j < 4; ++j)
      dst[j] = *(const s8v*)(A + (size_t)(ar0 + j * 64) * lda + kb + akc * 8);
  };
  auto loadB = [&](float2* dst, int kb) {
    const int row = n0 + br0;
    const int kk = kb + bq * 4;
    if (row < N) {
      dst[0] = *(const float2*)(B + (size_t)row * ldb + kk);
      dst[1] = *(const float2*)(B + (size_t)row * ldb + kk + 2);
    } else {
      dst[0].x = 0.f; dst[0].y = 0.f; dst[1].x = 0.f; dst[1].y = 0.f;
    }
  };
  auto stage = [&](const s8v* av, const float2* bv) {
    #pragma unroll
    for (int j = 0; j < 4; ++j)
      *(s8v*)(As + (ar0 + j * 64) * 40 + akc * 8) = av[j];
    unsigned int p0 = (unsigned int)f2b(bv[0].x) | ((unsigned int)f2b(bv[0].y) << 16);
    unsigned int p1 = (unsigned int)f2b(bv[1].x) | ((unsigned int)f2b(bv[1].y) << 16);
    uint2 pk; pk.x = p0; pk.y = p1;
    *(uint2*)(Bs + br0 * 40 + bq * 4) = pk;
  };
  auto domfma = [&]() {
    s8v af[4], bf[2];
    #pragma unroll
    for (int fm = 0; fm < 4; ++fm)
      af[fm] = *(const s8v*)(As + (w * 64 + fm * 16 + lr) * 40 + lk * 8);
    #pragma unroll
    for (int fn = 0; fn < 2; ++fn)
      bf[fn] = *(const s8v*)(Bs + (fn * 16 + lr) * 40 + lk * 8);
    #pragma unroll
    for (int fm = 0; fm < 4; ++fm)
      #pragma unroll
      for (int fn = 0; fn < 2; ++fn)
        acc[fm][fn] = __builtin_amdgcn_mfma_f32_16x16x32_bf16(af[fm], bf[fn], acc[fm][fn], 0, 0, 0);
  };

  int kb = kstart;
  if (nfull > 0) {
    loadA(a_cur, kb); loadB(b_cur, kb);
    for (int s = 0; s < nfull; ++s) {
      stage(a_cur, b_cur);
      __syncthreads();
      const bool more = (s + 1 < nfull);
      if (more) { loadA(a_nxt, kb + 32); loadB(b_nxt, kb + 32); }
      domfma();
      __syncthreads();
      if (more) {
        #pragma unroll
        for (int j = 0; j < 4; ++j) a_cur[j] = a_nxt[j];
        b_cur[0] = b_nxt[0]; b_cur[1] = b_nxt[1];
        kb += 32;
      }
    }
    kb += 32;
  }
  if (rem) {
    // Only reachable in the LAST chunk (kchunk % 32 == 0) -> kend == K.
    loadA(a_cur, kb);   // A pads zero by construction
    {
      const int row = n0 + br0;
      const int kk = kb + bq * 4;
      float e[4];
      #pragma unroll
      for (int v = 0; v < 4; ++v)
        e[v] = (row < N && kk + v < kend) ? B[(size_t)row * ldb + kk + v] : 0.f;
      b_cur[0].x = e[0]; b_cur[0].y = e[1]; b_cur[1].x = e[2]; b_cur[1].y = e[3];
    }
    stage(a_cur, b_cur);
    __syncthreads();
    domfma();
    __syncthreads();
  }

  float* Pk = P + ((size_t)ky * NT + nt) * 8192;
  #pragma unroll
  for (int fm = 0; fm < 4; ++fm)
    #pragma unroll
    for (int fn = 0; fn < 2; ++fn) {
      const int lcol = fn * 16 + lr;
      #pragma unroll
      for (int j = 0; j < 4; ++j) {
        const int row = w * 64 + fm * 16 + lk * 4 + j;
        Pk[row * 32 + lcol] = acc[fm][fn][j];
      }
    }
}

// ---------------------------------------------------------------------------
// Reduce over KS tile-major partials + epilogue. Grid = NT*4 blocks; block
// (nt, rpart) covers 64 rows of tile nt via 2 x float4 per thread.
// ---------------------------------------------------------------------------
template<bool BN, bool RES, bool WRD, bool WRT, bool F32OUT>
__global__ __launch_bounds__(256)
void reduce_k(const float* __restrict__ P, int KS, int NT, int N,
              const float* __restrict__ bias,
              const float* __restrict__ g, const float* __restrict__ bb,
              const float* __restrict__ rm, const float* __restrict__ rv,
              float* __restrict__ dR, int lddr,
              unsigned short* __restrict__ Cb, int ldc,
              unsigned short* __restrict__ Ct, float* __restrict__ Cf)
{
  const int bid = (int)blockIdx.x;
  const int nt = bid >> 2, rpart = bid & 3;
  const int n0 = nt << 5;
  const int t = threadIdx.x;
  const float* Pt = P + (size_t)nt * 8192;

  #pragma unroll
  for (int q = 0; q < 2; ++q) {
    const int i4 = rpart * 512 + q * 256 + t;   // float4 index within tile
    const int row = i4 >> 3;
    const int cb = (i4 & 7) * 4;
    float vv[4] = {0.f, 0.f, 0.f, 0.f};
    for (int kk = 0; kk < KS; ++kk) {
      const float4 pv = *(const float4*)(Pt + (size_t)kk * NT * 8192 + (size_t)i4 * 4);
      vv[0] += pv.x; vv[1] += pv.y; vv[2] += pv.z; vv[3] += pv.w;
    }
    #pragma unroll
    for (int e = 0; e < 4; ++e) {
      const int col = n0 + cb + e;
      if (col >= N) {
        if (!WRT && !F32OUT) Cb[(size_t)row * ldc + col] = 0;
        continue;
      }
      float v = vv[e] + bias[col];
      if (BN) { const float s = g[col] * rsqrtf(rv[col] + EPS); v = (v - rm[col]) * s + bb[col]; }
      v = fmaxf(v, 0.f);
      if (RES) v += dR[(size_t)row * lddr + col];
      if (WRD) dR[(size_t)row * lddr + col] = v;
      if (F32OUT) Cf[(size_t)row * N + col] = v;
      else if (WRT) Ct[(size_t)col * 256 + row] = f2b(v);
      else Cb[(size_t)row * ldc + col] = f2b(v);
    }
  }
}

// ---------------------------------------------------------------------------
// Prep: pack x-geno to bf16, pack env rows, zero h5b pads.
// ---------------------------------------------------------------------------
__global__ __launch_bounds__(256)
void prep_k(const float* __restrict__ x, unsigned short* __restrict__ xg,
            unsigned short* __restrict__ envb, unsigned short* __restrict__ h5b)
{
  const int bid = (int)blockIdx.x, t = threadIdx.x;
  if (bid < 16384) {
    const int idx = bid * 256 + t;
    const int r = idx >> 14, c = idx & 16383;
    xg[idx] = f2b(x[(size_t)r * 16437 + c]);
  } else if (bid < 16456) {
    const int idx = (bid - 16384) * 256 + t;
    const int b = idx / 72, c = idx % 72;
    envb[idx] = (c < 53) ? f2b(x[(size_t)b * 16437 + 16384 + c]) : (unsigned short)0;
  } else {
    for (int z = t; z < 256 * 14; z += 256) {
      const int b = z / 14, j = z % 14;
      h5b[(size_t)b * 13344 + 13330 + j] = 0;
    }
  }
}

// ---------------------------------------------------------------------------
// Fused head: per unit i, 4 chained 256x64x64 GEMMs in LDS/regs (unchanged).
// ---------------------------------------------------------------------------
__global__ __launch_bounds__(256, 2)
void fused_head(const unsigned short* __restrict__ envb,
                const unsigned short* __restrict__ htr,
                const float* __restrict__ Wlin, const float* __restrict__ blin,
                const float* __restrict__ W13, const float* __restrict__ b13,
                const float* __restrict__ W14, const float* __restrict__ b14,
                const float* __restrict__ W15, const float* __restrict__ b15,
                const float* __restrict__ bn3g, const float* __restrict__ bn3b,
                const float* __restrict__ bn3rm, const float* __restrict__ bn3rv,
                unsigned short* __restrict__ h5b)
{
  __shared__ unsigned short act[256 * 72];
  __shared__ unsigned short Wl[64 * 72];
  __shared__ unsigned short Wa[64 * 72];
  __shared__ unsigned short Wb[16 * 72];
  const int i = (int)blockIdx.x;
  const int t = threadIdx.x, lane = t & 63, w = t >> 6;
  const int lr = lane & 15, lk = lane >> 4;
  const int R = 2666;

  #pragma unroll
  for (int c8 = 0; c8 < 9; ++c8)
    *(s8v*)(act + t * 72 + c8 * 8) = *(const s8v*)(envb + t * 72 + c8 * 8);
  act[t * 72 + 53] = htr[(size_t)i * 256 + t];

  const float* wli = Wlin + (size_t)i * 2916;
  for (int idx = t; idx < 64 * 72; idx += 256) {
    const int r = idx / 72, f = idx % 72;
    Wl[idx] = (r < 54 && f < 54) ? f2b(wli[r * 54 + f]) : (unsigned short)0;
    Wa[idx] = (r < 54 && f < 54) ? f2b(W13[r * 54 + f]) : (unsigned short)0;
  }
  for (int idx = t; idx < 16 * 72; idx += 256) {
    const int r = idx / 72, f = idx % 72;
    Wb[idx] = (r < 5 && f < 54) ? f2b(W15[r * 54 + f]) : (unsigned short)0;
  }
  const float s0 = bn3g[i] * rsqrtf(bn3rv[i] + EPS), m0 = bn3rm[i], c0 = bn3b[i];
  const float s1 = bn3g[R+i] * rsqrtf(bn3rv[R+i] + EPS), m1 = bn3rm[R+i], c1 = bn3b[R+i];
  const float s2 = bn3g[2*R+i] * rsqrtf(bn3rv[2*R+i] + EPS), m2 = bn3rm[2*R+i], c2 = bn3b[2*R+i];
  __syncthreads();

  const int abase = (w * 64 + lr) * 72 + lk * 8;
  f4v acc[4][4];

  auto zacc = [&]() {
    #pragma unroll
    for (int a = 0; a < 4; ++a)
      #pragma unroll
      for (int b = 0; b < 4; ++b) acc[a][b] = f4v{0.f, 0.f, 0.f, 0.f};
  };
  auto gemm4 = [&](const unsigned short* B) {
    s8v af[2][4];
    #pragma unroll
    for (int ks = 0; ks < 2; ++ks)
      #pragma unroll
      for (int fm = 0; fm < 4; ++fm)
        af[ks][fm] = *(const s8v*)(act + abase + fm * 16 * 72 + ks * 32);
    #pragma unroll
    for (int fn = 0; fn < 4; ++fn) {
      s8v b0 = *(const s8v*)(B + (fn * 16 + lr) * 72 + lk * 8);
      s8v b1 = *(const s8v*)(B + (fn * 16 + lr) * 72 + 32 + lk * 8);
      #pragma unroll
      for (int fm = 0; fm < 4; ++fm) {
        acc[fm][fn] = __builtin_amdgcn_mfma_f32_16x16x32_bf16(af[0][fm], b0, acc[fm][fn], 0, 0, 0);
        acc[fm][fn] = __builtin_amdgcn_mfma_f32_16x16x32_bf16(af[1][fm], b1, acc[fm][fn], 0, 0, 0);
      }
    }
  };
  auto epi_bn = [&](const float* bias, float s, float m, float c) {
    #pragma unroll
    for (int fn = 0; fn < 4; ++fn) {
      const int o = fn * 16 + lr;
      const float bo = (o < 54) ? bias[o] : 0.f;
      #pragma unroll
      for (int fm = 0; fm < 4; ++fm)
        #pragma unroll
        for (int j = 0; j < 4; ++j) {
          const int row = w * 64 + fm * 16 + lk * 4 + j;
          float v = acc[fm][fn][j] + bo;
          v = (v - m) * s + c;
          v = fmaxf(v, 0.f);
          act[row * 72 + o] = (o < 54) ? f2b(v) : (unsigned short)0;
        }
    }
  };

  zacc(); gemm4(Wl);
  #pragma unroll
  for (int fn = 0; fn < 4; ++fn) {
    const int o = fn * 16 + lr;
    const float bl = (o < 54) ? blin[(size_t)i * 54 + o] : 0.f;
    #pragma unroll
    for (int fm = 0; fm < 4; ++fm)
      #pragma unroll
      for (int j = 0; j < 4; ++j) {
        const int row = w * 64 + fm * 16 + lk * 4 + j;
        float v = acc[fm][fn][j] + bl;
        act[row * 72 + o] = (o < 54) ? f2b(v) : (unsigned short)0;
      }
  }
  __syncthreads();
  for (int idx = t; idx < 64 * 72; idx += 256) {
    const int r = idx / 72, f = idx % 72;
    Wl[idx] = (r < 54 && f < 54) ? f2b(W14[r * 54 + f]) : (unsigned short)0;
  }
  zacc(); gemm4(Wa); epi_bn(b13, s0, m0, c0);
  __syncthreads();
  zacc(); gemm4(Wl); epi_bn(b14, s1, m1, c1);
  f4v a4[4] = {};
  {
    s8v af[2][4];
    #pragma unroll
    for (int ks = 0; ks < 2; ++ks)
      #pragma unroll
      for (int fm = 0; fm < 4; ++fm)
        af[ks][fm] = *(const s8v*)(act + abase + fm * 16 * 72 + ks * 32);
    s8v b0 = *(const s8v*)(Wb + lr * 72 + lk * 8);
    s8v b1 = *(const s8v*)(Wb + lr * 72 + 32 + lk * 8);
    #pragma unroll
    for (int fm = 0; fm < 4; ++fm) {
      a4[fm] = __builtin_amdgcn_mfma_f32_16x16x32_bf16(af[0][fm], b0, a4[fm], 0, 0, 0);
      a4[fm] = __builtin_amdgcn_mfma_f32_16x16x32_bf16(af[1][fm], b1, a4[fm], 0, 0, 0);
    }
  }
  if (lr < 5) {
    const float b5 = b15[lr];
    #pragma unroll
    for (int fm = 0; fm < 4; ++fm)
      #pragma unroll
      for (int j = 0; j < 4; ++j) {
        const int row = w * 64 + fm * 16 + lk * 4 + j;
        float v = a4[fm][j] + b5;
        v = (v - m2) * s2 + c2;
        v = fmaxf(v, 0.f);
        h5b[(size_t)row * 13344 + (size_t)i * 5 + lr] = f2b(v);
      }
  }
}

extern "C" void kernel_launch(void* const* d_in, const int* in_sizes, int n_in,
                              void* d_out, int out_size, void* d_ws, size_t ws_size,
                              hipStream_t stream)
{
  const float* x    = (const float*)d_in[0];
  const float* W1   = (const float*)d_in[1];
  const float* b1   = (const float*)d_in[2];
  const float* Wmid = (const float*)d_in[3];
  const float* bmid = (const float*)d_in[4];
  const float* bng  = (const float*)d_in[5];
  const float* bnb  = (const float*)d_in[6];
  const float* bnrm = (const float*)d_in[7];
  const float* bnrv = (const float*)d_in[8];
  const float* Wlin = (const float*)d_in[9];
  const float* blin = (const float*)d_in[10];
  const float* W13  = (const float*)d_in[11];
  const float* b13  = (const float*)d_in[12];
  const float* W14  = (const float*)d_in[13];
  const float* b14  = (const float*)d_in[14];
  const float* W15  = (const float*)d_in[15];
  const float* b15  = (const float*)d_in[16];
  const float* bn3g = (const float*)d_in[17];
  const float* bn3b = (const float*)d_in[18];
  const float* bn3rm= (const float*)d_in[19];
  const float* bn3rv= (const float*)d_in[20];
  const float* W16  = (const float*)d_in[21];
  const float* b16  = (const float*)d_in[22];
  const float* W17  = (const float*)d_in[23];
  const float* b17  = (const float*)d_in[24];
  const float* W18  = (const float*)d_in[25];
  const float* b18  = (const float*)d_in[26];

  const int R = 2666;
  char* p = (char*)d_ws;
  unsigned short* xg  = (unsigned short*)p; p += (size_t)256 * 16384 * 2;
  unsigned short* hA  = (unsigned short*)p; p += (size_t)256 * 2688 * 2;
  unsigned short* hB  = (unsigned short*)p; p += (size_t)256 * 2688 * 2;
  float*          dR  = (float*)p;          p += (size_t)256 * 2688 * 4;
  unsigned short* h5b = (unsigned short*)p; p += (size_t)256 * 13344 * 2;
  unsigned short* h6b = (unsigned short*)p; p += (size_t)256 * 768 * 2;
  unsigned short* h7b = (unsigned short*)p; p += (size_t)256 * 768 * 2;
  unsigned short* envb= (unsigned short*)p; p += (size_t)256 * 72 * 2;
  unsigned short* htr = (unsigned short*)p; p += (size_t)2666 * 256 * 2;
  float* P = (float*)p;   // split-K partials, tile-major, <= 38.6 MB

  dim3 TB(256);

  prep_k<<<dim3(16457), TB, 0, stream>>>(x, xg, envb, h5b);

  // L1: K=16384, NT=84, KS=14, kchunk=1184 (37*32; 13*1184=15392, last=992)
  gemm_splitk<<<dim3(84 * 14), TB, 0, stream>>>(xg, 16384, W1, 16384, P, 84, R, 16384, 1184, 14);
  reduce_k<true, false, true, false, false><<<dim3(84 * 4), TB, 0, stream>>>(
      P, 14, 84, R, b1, bng, bnb, bnrm, bnrv, dR, 2688, hA, 2688, nullptr, nullptr);

  // mids: K=2666, NT=84, KS=14, kchunk=192 (6*32; last chunk 170, rem=10)
  unsigned short* cur = hA; unsigned short* nxt = hB;
  for (int k = 0; k < 11; ++k) {
    const float* bw = Wmid + (size_t)k * R * R;
    const float* bs = bmid + (size_t)k * R;
    const int L = k + 1;
    gemm_splitk<<<dim3(84 * 14), TB, 0, stream>>>(cur, 2688, bw, R, P, 84, R, R, 192, 14);
    if (k == 10)
      reduce_k<true, false, false, true, false><<<dim3(84 * 4), TB, 0, stream>>>(
          P, 14, 84, R, bs, bng + (size_t)L * R, bnb + (size_t)L * R,
          bnrm + (size_t)L * R, bnrv + (size_t)L * R,
          nullptr, 0, nullptr, 2688, htr, nullptr);
    else if ((k & 1) == 0)
      reduce_k<true, false, false, false, false><<<dim3(84 * 4), TB, 0, stream>>>(
          P, 14, 84, R, bs, bng + (size_t)L * R, bnb + (size_t)L * R,
          bnrm + (size_t)L * R, bnrv + (size_t)L * R,
          nullptr, 0, nxt, 2688, nullptr, nullptr);
    else
      reduce_k<true, true, true, false, false><<<dim3(84 * 4), TB, 0, stream>>>(
          P, 14, 84, R, bs, bng + (size_t)L * R, bnb + (size_t)L * R,
          bnrm + (size_t)L * R, bnrv + (size_t)L * R,
          dR, 2688, nxt, 2688, nullptr, nullptr);
    unsigned short* tmp = cur; cur = nxt; nxt = tmp;
  }

  // Fused d3 -> W13 -> W14 -> W15 chain
  fused_head<<<dim3(2666), TB, 0, stream>>>(
      envb, htr, Wlin, blin, W13, b13, W14, b14, W15, b15,
      bn3g, bn3b, bn3rm, bn3rv, h5b);

  // W16: K=13330, NT=24, KS=16, kchunk=864 (27*32; last 12960..13330, rem=18)
  gemm_splitk<<<dim3(24 * 16), TB, 0, stream>>>(h5b, 13344, W16, 13330, P, 24, 750, 13330, 864, 16);
  reduce_k<false, false, false, false, false><<<dim3(24 * 4), TB, 0, stream>>>(
      P, 16, 24, 750, b16, nullptr, nullptr, nullptr, nullptr,
      nullptr, 0, h6b, 768, nullptr, nullptr);

  // W17: K=750, KS=8, kchunk=96 (last chunk 672..750, rem=14)
  gemm_splitk<<<dim3(24 * 8), TB, 0, stream>>>(h6b, 768, W17, 750, P, 24, 750, 750, 96, 8);
  reduce_k<false, false, false, false, false><<<dim3(24 * 4), TB, 0, stream>>>(
      P, 8, 24, 750, b17, nullptr, nullptr, nullptr, nullptr,
      nullptr, 0, h7b, 768, nullptr, nullptr);

  // W18 -> f32 d_out
  gemm_splitk<<<dim3(24 * 8), TB, 0, stream>>>(h7b, 768, W18, 750, P, 24, 750, 750, 96, 8);
  reduce_k<false, false, false, false, true><<<dim3(24 * 4), TB, 0, stream>>>(
      P, 8, 24, 750, b18, nullptr, nullptr, nullptr, nullptr,
      nullptr, 0, nullptr, 768, nullptr, (float*)d_out);
}

// Round 7
// 643.987 us; speedup vs baseline: 3.6457x; 1.2496x over previous
//
#include <hip/hip_runtime.h>

#define EPS 1e-5f

typedef __attribute__((ext_vector_type(8))) short s8v;   // 8 x bf16 bits
typedef __attribute__((ext_vector_type(4))) float f4v;   // MFMA accumulator

__device__ __forceinline__ unsigned short f2b(float x) {
  unsigned int u = __float_as_uint(x);
  u += 0x7FFFu + ((u >> 16) & 1u);
  return (unsigned short)(u >> 16);
}
__device__ __forceinline__ float b2f(unsigned short b) {
  return __uint_as_float(((unsigned int)b) << 16);
}

// ---------------------------------------------------------------------------
// Split-K GEMM, partials only (kernel boundary = the global sync; NO fences).
//   A: 256 x K bf16 (lda mult of 32, zero-padded)
//   B: N x K f32 row-major
//   Block computes a 256 x 64 panel (TWO 32-col tiles) per K-chunk:
//   A staged once per k-step feeds 16 MFMA/wave (2x the old ratio).
//   bid: ky = bid % KS, ntp = bid / KS; tiles nt = 2*ntp, 2*ntp+1.
//   Partials tile-major: P[(ky*NT + nt)*8192 + row*32 + lcol] (32 KB/tile).
//   HOST INVARIANT: kchunk % 32 == 0 (round-4 lesson).
// ---------------------------------------------------------------------------
__global__ __launch_bounds__(256)
void gemm_splitk(const unsigned short* __restrict__ A, int lda,
                 const float* __restrict__ B, int ldb,
                 float* __restrict__ P, int NT, int N, int K, int kchunk, int KS)
{
  __shared__ unsigned short As[256 * 40];
  __shared__ unsigned short Bs[64 * 40];
  const int bid = (int)blockIdx.x;
  const int ky = bid % KS, ntp = bid / KS;
  const int n0 = ntp << 6;
  const int t = threadIdx.x, lane = t & 63, w = t >> 6;
  const int lr = lane & 15, lk = lane >> 4;

  const int kstart = ky * kchunk;
  const int kend = min(K, kstart + kchunk);
  const int nfull = (kend - kstart) >> 5;
  const int rem = (kend - kstart) & 31;

  const int ar0 = t >> 2, akc = t & 3;   // A: rows ar0 + j*64, 8-bf16 chunk akc
  const int br0 = t >> 2, bq = t & 3;    // B: row br0 (0..63), col-octet bq

  f4v acc[4][4] = {};
  s8v a_cur[4]; float2 b_cur[4];
  s8v a_nxt[4]; float2 b_nxt[4];

  auto loadA = [&](s8v* dst, int kb) {
    #pragma unroll
    for (int j = 0; j < 4; ++j)
      dst[j] = *(const s8v*)(A + (size_t)(ar0 + j * 64) * lda + kb + akc * 8);
  };
  auto loadB = [&](float2* dst, int kb) {
    const int row = n0 + br0;
    const int kk = kb + bq * 8;
    if (row < N) {
      #pragma unroll
      for (int j = 0; j < 4; ++j)
        dst[j] = *(const float2*)(B + (size_t)row * ldb + kk + 2 * j);
    } else {
      #pragma unroll
      for (int j = 0; j < 4; ++j) { dst[j].x = 0.f; dst[j].y = 0.f; }
    }
  };
  auto stage = [&](const s8v* av, const float2* bv) {
    #pragma unroll
    for (int j = 0; j < 4; ++j)
      *(s8v*)(As + (ar0 + j * 64) * 40 + akc * 8) = av[j];
    s8v pk;
    #pragma unroll
    for (int j = 0; j < 4; ++j) {
      pk[2 * j]     = (short)f2b(bv[j].x);
      pk[2 * j + 1] = (short)f2b(bv[j].y);
    }
    *(s8v*)(Bs + br0 * 40 + bq * 8) = pk;
  };
  auto domfma = [&]() {
    s8v af[4];
    #pragma unroll
    for (int fm = 0; fm < 4; ++fm)
      af[fm] = *(const s8v*)(As + (w * 64 + fm * 16 + lr) * 40 + lk * 8);
    #pragma unroll
    for (int fn = 0; fn < 4; ++fn) {
      s8v bf = *(const s8v*)(Bs + (fn * 16 + lr) * 40 + lk * 8);
      #pragma unroll
      for (int fm = 0; fm < 4; ++fm)
        acc[fm][fn] = __builtin_amdgcn_mfma_f32_16x16x32_bf16(af[fm], bf, acc[fm][fn], 0, 0, 0);
    }
  };

  int kb = kstart;
  if (nfull > 0) {
    loadA(a_cur, kb); loadB(b_cur, kb);
    for (int s = 0; s < nfull; ++s) {
      stage(a_cur, b_cur);
      __syncthreads();
      const bool more = (s + 1 < nfull);
      if (more) { loadA(a_nxt, kb + 32); loadB(b_nxt, kb + 32); }
      domfma();
      __syncthreads();
      if (more) {
        #pragma unroll
        for (int j = 0; j < 4; ++j) a_cur[j] = a_nxt[j];
        #pragma unroll
        for (int j = 0; j < 4; ++j) b_cur[j] = b_nxt[j];
        kb += 32;
      }
    }
    kb += 32;
  }
  if (rem) {
    // Only reachable in the LAST chunk (kchunk % 32 == 0) -> kend == K.
    loadA(a_cur, kb);   // A pads zero by construction
    {
      const int row = n0 + br0;
      const int kk = kb + bq * 8;
      #pragma unroll
      for (int j = 0; j < 4; ++j) {
        const int k0 = kk + 2 * j;
        b_cur[j].x = (row < N && k0     < kend) ? B[(size_t)row * ldb + k0]     : 0.f;
        b_cur[j].y = (row < N && k0 + 1 < kend) ? B[(size_t)row * ldb + k0 + 1] : 0.f;
      }
    }
    stage(a_cur, b_cur);
    __syncthreads();
    domfma();
    __syncthreads();
  }

  #pragma unroll
  for (int fn = 0; fn < 4; ++fn) {
    float* Pk = P + ((size_t)ky * NT + (ntp * 2 + (fn >> 1))) * 8192;
    const int lcol = (fn & 1) * 16 + lr;
    #pragma unroll
    for (int fm = 0; fm < 4; ++fm)
      #pragma unroll
      for (int j = 0; j < 4; ++j) {
        const int row = w * 64 + fm * 16 + lk * 4 + j;
        Pk[row * 32 + lcol] = acc[fm][fn][j];
      }
  }
}

// ---------------------------------------------------------------------------
// Reduce over KS tile-major partials + epilogue. Grid = NT*4 blocks; block
// (nt, rpart) covers 64 rows of tile nt via 2 x float4 per thread.
// ---------------------------------------------------------------------------
template<bool BN, bool RES, bool WRD, bool WRT, bool F32OUT>
__global__ __launch_bounds__(256)
void reduce_k(const float* __restrict__ P, int KS, int NT, int N,
              const float* __restrict__ bias,
              const float* __restrict__ g, const float* __restrict__ bb,
              const float* __restrict__ rm, const float* __restrict__ rv,
              float* __restrict__ dR, int lddr,
              unsigned short* __restrict__ Cb, int ldc,
              unsigned short* __restrict__ Ct, float* __restrict__ Cf)
{
  const int bid = (int)blockIdx.x;
  const int nt = bid >> 2, rpart = bid & 3;
  const int n0 = nt << 5;
  const int t = threadIdx.x;
  const float* Pt = P + (size_t)nt * 8192;

  #pragma unroll
  for (int q = 0; q < 2; ++q) {
    const int i4 = rpart * 512 + q * 256 + t;   // float4 index within tile
    const int row = i4 >> 3;
    const int cb = (i4 & 7) * 4;
    float vv[4] = {0.f, 0.f, 0.f, 0.f};
    for (int kk = 0; kk < KS; ++kk) {
      const float4 pv = *(const float4*)(Pt + (size_t)kk * NT * 8192 + (size_t)i4 * 4);
      vv[0] += pv.x; vv[1] += pv.y; vv[2] += pv.z; vv[3] += pv.w;
    }
    #pragma unroll
    for (int e = 0; e < 4; ++e) {
      const int col = n0 + cb + e;
      if (col >= N) {
        if (!WRT && !F32OUT) Cb[(size_t)row * ldc + col] = 0;
        continue;
      }
      float v = vv[e] + bias[col];
      if (BN) { const float s = g[col] * rsqrtf(rv[col] + EPS); v = (v - rm[col]) * s + bb[col]; }
      v = fmaxf(v, 0.f);
      if (RES) v += dR[(size_t)row * lddr + col];
      if (WRD) dR[(size_t)row * lddr + col] = v;
      if (F32OUT) Cf[(size_t)row * N + col] = v;
      else if (WRT) Ct[(size_t)col * 256 + row] = f2b(v);
      else Cb[(size_t)row * ldc + col] = f2b(v);
    }
  }
}

// ---------------------------------------------------------------------------
// Prep: pack x-geno to bf16, pack env rows, zero h5b pads.
// ---------------------------------------------------------------------------
__global__ __launch_bounds__(256)
void prep_k(const float* __restrict__ x, unsigned short* __restrict__ xg,
            unsigned short* __restrict__ envb, unsigned short* __restrict__ h5b)
{
  const int bid = (int)blockIdx.x, t = threadIdx.x;
  if (bid < 16384) {
    const int idx = bid * 256 + t;
    const int r = idx >> 14, c = idx & 16383;
    xg[idx] = f2b(x[(size_t)r * 16437 + c]);
  } else if (bid < 16456) {
    const int idx = (bid - 16384) * 256 + t;
    const int b = idx / 72, c = idx % 72;
    envb[idx] = (c < 53) ? f2b(x[(size_t)b * 16437 + 16384 + c]) : (unsigned short)0;
  } else {
    for (int z = t; z < 256 * 14; z += 256) {
      const int b = z / 14, j = z % 14;
      h5b[(size_t)b * 13344 + 13330 + j] = 0;
    }
  }
}

// ---------------------------------------------------------------------------
// Fused head: per unit i, 4 chained 256x64x64 GEMMs in LDS/regs (unchanged).
// ---------------------------------------------------------------------------
__global__ __launch_bounds__(256, 2)
void fused_head(const unsigned short* __restrict__ envb,
                const unsigned short* __restrict__ htr,
                const float* __restrict__ Wlin, const float* __restrict__ blin,
                const float* __restrict__ W13, const float* __restrict__ b13,
                const float* __restrict__ W14, const float* __restrict__ b14,
                const float* __restrict__ W15, const float* __restrict__ b15,
                const float* __restrict__ bn3g, const float* __restrict__ bn3b,
                const float* __restrict__ bn3rm, const float* __restrict__ bn3rv,
                unsigned short* __restrict__ h5b)
{
  __shared__ unsigned short act[256 * 72];
  __shared__ unsigned short Wl[64 * 72];
  __shared__ unsigned short Wa[64 * 72];
  __shared__ unsigned short Wb[16 * 72];
  const int i = (int)blockIdx.x;
  const int t = threadIdx.x, lane = t & 63, w = t >> 6;
  const int lr = lane & 15, lk = lane >> 4;
  const int R = 2666;

  #pragma unroll
  for (int c8 = 0; c8 < 9; ++c8)
    *(s8v*)(act + t * 72 + c8 * 8) = *(const s8v*)(envb + t * 72 + c8 * 8);
  act[t * 72 + 53] = htr[(size_t)i * 256 + t];

  const float* wli = Wlin + (size_t)i * 2916;
  for (int idx = t; idx < 64 * 72; idx += 256) {
    const int r = idx / 72, f = idx % 72;
    Wl[idx] = (r < 54 && f < 54) ? f2b(wli[r * 54 + f]) : (unsigned short)0;
    Wa[idx] = (r < 54 && f < 54) ? f2b(W13[r * 54 + f]) : (unsigned short)0;
  }
  for (int idx = t; idx < 16 * 72; idx += 256) {
    const int r = idx / 72, f = idx % 72;
    Wb[idx] = (r < 5 && f < 54) ? f2b(W15[r * 54 + f]) : (unsigned short)0;
  }
  const float s0 = bn3g[i] * rsqrtf(bn3rv[i] + EPS), m0 = bn3rm[i], c0 = bn3b[i];
  const float s1 = bn3g[R+i] * rsqrtf(bn3rv[R+i] + EPS), m1 = bn3rm[R+i], c1 = bn3b[R+i];
  const float s2 = bn3g[2*R+i] * rsqrtf(bn3rv[2*R+i] + EPS), m2 = bn3rm[2*R+i], c2 = bn3b[2*R+i];
  __syncthreads();

  const int abase = (w * 64 + lr) * 72 + lk * 8;
  f4v acc[4][4];

  auto zacc = [&]() {
    #pragma unroll
    for (int a = 0; a < 4; ++a)
      #pragma unroll
      for (int b = 0; b < 4; ++b) acc[a][b] = f4v{0.f, 0.f, 0.f, 0.f};
  };
  auto gemm4 = [&](const unsigned short* B) {
    s8v af[2][4];
    #pragma unroll
    for (int ks = 0; ks < 2; ++ks)
      #pragma unroll
      for (int fm = 0; fm < 4; ++fm)
        af[ks][fm] = *(const s8v*)(act + abase + fm * 16 * 72 + ks * 32);
    #pragma unroll
    for (int fn = 0; fn < 4; ++fn) {
      s8v b0 = *(const s8v*)(B + (fn * 16 + lr) * 72 + lk * 8);
      s8v b1 = *(const s8v*)(B + (fn * 16 + lr) * 72 + 32 + lk * 8);
      #pragma unroll
      for (int fm = 0; fm < 4; ++fm) {
        acc[fm][fn] = __builtin_amdgcn_mfma_f32_16x16x32_bf16(af[0][fm], b0, acc[fm][fn], 0, 0, 0);
        acc[fm][fn] = __builtin_amdgcn_mfma_f32_16x16x32_bf16(af[1][fm], b1, acc[fm][fn], 0, 0, 0);
      }
    }
  };
  auto epi_bn = [&](const float* bias, float s, float m, float c) {
    #pragma unroll
    for (int fn = 0; fn < 4; ++fn) {
      const int o = fn * 16 + lr;
      const float bo = (o < 54) ? bias[o] : 0.f;
      #pragma unroll
      for (int fm = 0; fm < 4; ++fm)
        #pragma unroll
        for (int j = 0; j < 4; ++j) {
          const int row = w * 64 + fm * 16 + lk * 4 + j;
          float v = acc[fm][fn][j] + bo;
          v = (v - m) * s + c;
          v = fmaxf(v, 0.f);
          act[row * 72 + o] = (o < 54) ? f2b(v) : (unsigned short)0;
        }
    }
  };

  zacc(); gemm4(Wl);
  #pragma unroll
  for (int fn = 0; fn < 4; ++fn) {
    const int o = fn * 16 + lr;
    const float bl = (o < 54) ? blin[(size_t)i * 54 + o] : 0.f;
    #pragma unroll
    for (int fm = 0; fm < 4; ++fm)
      #pragma unroll
      for (int j = 0; j < 4; ++j) {
        const int row = w * 64 + fm * 16 + lk * 4 + j;
        float v = acc[fm][fn][j] + bl;
        act[row * 72 + o] = (o < 54) ? f2b(v) : (unsigned short)0;
      }
  }
  __syncthreads();
  for (int idx = t; idx < 64 * 72; idx += 256) {
    const int r = idx / 72, f = idx % 72;
    Wl[idx] = (r < 54 && f < 54) ? f2b(W14[r * 54 + f]) : (unsigned short)0;
  }
  zacc(); gemm4(Wa); epi_bn(b13, s0, m0, c0);
  __syncthreads();
  zacc(); gemm4(Wl); epi_bn(b14, s1, m1, c1);
  f4v a4[4] = {};
  {
    s8v af[2][4];
    #pragma unroll
    for (int ks = 0; ks < 2; ++ks)
      #pragma unroll
      for (int fm = 0; fm < 4; ++fm)
        af[ks][fm] = *(const s8v*)(act + abase + fm * 16 * 72 + ks * 32);
    s8v b0 = *(const s8v*)(Wb + lr * 72 + lk * 8);
    s8v b1 = *(const s8v*)(Wb + lr * 72 + 32 + lk * 8);
    #pragma unroll
    for (int fm = 0; fm < 4; ++fm) {
      a4[fm] = __builtin_amdgcn_mfma_f32_16x16x32_bf16(af[0][fm], b0, a4[fm], 0, 0, 0);
      a4[fm] = __builtin_amdgcn_mfma_f32_16x16x32_bf16(af[1][fm], b1, a4[fm], 0, 0, 0);
    }
  }
  if (lr < 5) {
    const float b5 = b15[lr];
    #pragma unroll
    for (int fm = 0; fm < 4; ++fm)
      #pragma unroll
      for (int j = 0; j < 4; ++j) {
        const int row = w * 64 + fm * 16 + lk * 4 + j;
        float v = a4[fm][j] + b5;
        v = (v - m2) * s2 + c2;
        v = fmaxf(v, 0.f);
        h5b[(size_t)row * 13344 + (size_t)i * 5 + lr] = f2b(v);
      }
  }
}

extern "C" void kernel_launch(void* const* d_in, const int* in_sizes, int n_in,
                              void* d_out, int out_size, void* d_ws, size_t ws_size,
                              hipStream_t stream)
{
  const float* x    = (const float*)d_in[0];
  const float* W1   = (const float*)d_in[1];
  const float* b1   = (const float*)d_in[2];
  const float* Wmid = (const float*)d_in[3];
  const float* bmid = (const float*)d_in[4];
  const float* bng  = (const float*)d_in[5];
  const float* bnb  = (const float*)d_in[6];
  const float* bnrm = (const float*)d_in[7];
  const float* bnrv = (const float*)d_in[8];
  const float* Wlin = (const float*)d_in[9];
  const float* blin = (const float*)d_in[10];
  const float* W13  = (const float*)d_in[11];
  const float* b13  = (const float*)d_in[12];
  const float* W14  = (const float*)d_in[13];
  const float* b14  = (const float*)d_in[14];
  const float* W15  = (const float*)d_in[15];
  const float* b15  = (const float*)d_in[16];
  const float* bn3g = (const float*)d_in[17];
  const float* bn3b = (const float*)d_in[18];
  const float* bn3rm= (const float*)d_in[19];
  const float* bn3rv= (const float*)d_in[20];
  const float* W16  = (const float*)d_in[21];
  const float* b16  = (const float*)d_in[22];
  const float* W17  = (const float*)d_in[23];
  const float* b17  = (const float*)d_in[24];
  const float* W18  = (const float*)d_in[25];
  const float* b18  = (const float*)d_in[26];

  const int R = 2666;
  char* p = (char*)d_ws;
  unsigned short* xg  = (unsigned short*)p; p += (size_t)256 * 16384 * 2;
  unsigned short* hA  = (unsigned short*)p; p += (size_t)256 * 2688 * 2;
  unsigned short* hB  = (unsigned short*)p; p += (size_t)256 * 2688 * 2;
  float*          dR  = (float*)p;          p += (size_t)256 * 2688 * 4;
  unsigned short* h5b = (unsigned short*)p; p += (size_t)256 * 13344 * 2;
  unsigned short* h6b = (unsigned short*)p; p += (size_t)256 * 768 * 2;
  unsigned short* h7b = (unsigned short*)p; p += (size_t)256 * 768 * 2;
  unsigned short* envb= (unsigned short*)p; p += (size_t)256 * 72 * 2;
  unsigned short* htr = (unsigned short*)p; p += (size_t)2666 * 256 * 2;
  float* P = (float*)p;   // split-K partials, tile-major, <= 28 MB

  dim3 TB(256);

  prep_k<<<dim3(16457), TB, 0, stream>>>(x, xg, envb, h5b);

  // L1: K=16384, NT=84 (42 pairs), KS=8, kchunk=2048 (64 steps, rem=0)
  gemm_splitk<<<dim3(42 * 8), TB, 0, stream>>>(xg, 16384, W1, 16384, P, 84, R, 16384, 2048, 8);
  reduce_k<true, false, true, false, false><<<dim3(84 * 4), TB, 0, stream>>>(
      P, 8, 84, R, b1, bng, bnb, bnrm, bnrv, dR, 2688, hA, 2688, nullptr, nullptr);

  // mids: K=2666, NT=84, KS=10, kchunk=288 (9 steps; last chunk 74 = 2*32+10)
  unsigned short* cur = hA; unsigned short* nxt = hB;
  for (int k = 0; k < 11; ++k) {
    const float* bw = Wmid + (size_t)k * R * R;
    const float* bs = bmid + (size_t)k * R;
    const int L = k + 1;
    gemm_splitk<<<dim3(42 * 10), TB, 0, stream>>>(cur, 2688, bw, R, P, 84, R, R, 288, 10);
    if (k == 10)
      reduce_k<true, false, false, true, false><<<dim3(84 * 4), TB, 0, stream>>>(
          P, 10, 84, R, bs, bng + (size_t)L * R, bnb + (size_t)L * R,
          bnrm + (size_t)L * R, bnrv + (size_t)L * R,
          nullptr, 0, nullptr, 2688, htr, nullptr);
    else if ((k & 1) == 0)
      reduce_k<true, false, false, false, false><<<dim3(84 * 4), TB, 0, stream>>>(
          P, 10, 84, R, bs, bng + (size_t)L * R, bnb + (size_t)L * R,
          bnrm + (size_t)L * R, bnrv + (size_t)L * R,
          nullptr, 0, nxt, 2688, nullptr, nullptr);
    else
      reduce_k<true, true, true, false, false><<<dim3(84 * 4), TB, 0, stream>>>(
          P, 10, 84, R, bs, bng + (size_t)L * R, bnb + (size_t)L * R,
          bnrm + (size_t)L * R, bnrv + (size_t)L * R,
          dR, 2688, nxt, 2688, nullptr, nullptr);
    unsigned short* tmp = cur; cur = nxt; nxt = tmp;
  }

  // Fused d3 -> W13 -> W14 -> W15 chain
  fused_head<<<dim3(2666), TB, 0, stream>>>(
      envb, htr, Wlin, blin, W13, b13, W14, b14, W15, b15,
      bn3g, bn3b, bn3rm, bn3rv, h5b);

  // W16: K=13330, NT=24, KS=27, kchunk=512 (16 steps; last chunk 18)
  gemm_splitk<<<dim3(12 * 27), TB, 0, stream>>>(h5b, 13344, W16, 13330, P, 24, 750, 13330, 512, 27);
  reduce_k<false, false, false, false, false><<<dim3(24 * 4), TB, 0, stream>>>(
      P, 27, 24, 750, b16, nullptr, nullptr, nullptr, nullptr,
      nullptr, 0, h6b, 768, nullptr, nullptr);

  // W17: K=750, KS=8, kchunk=96 (3 steps; last chunk 78 = 2*32+14)
  gemm_splitk<<<dim3(12 * 8), TB, 0, stream>>>(h6b, 768, W17, 750, P, 24, 750, 750, 96, 8);
  reduce_k<false, false, false, false, false><<<dim3(24 * 4), TB, 0, stream>>>(
      P, 8, 24, 750, b17, nullptr, nullptr, nullptr, nullptr,
      nullptr, 0, h7b, 768, nullptr, nullptr);

  // W18 -> f32 d_out
  gemm_splitk<<<dim3(12 * 8), TB, 0, stream>>>(h7b, 768, W18, 750, P, 24, 750, 750, 96, 8);
  reduce_k<false, false, false, false, true><<<dim3(24 * 4), TB, 0, stream>>>(
      P, 8, 24, 750, b18, nullptr, nullptr, nullptr, nullptr,
      nullptr, 0, nullptr, 768, nullptr, (float*)d_out);
}

// Round 8
// 605.047 us; speedup vs baseline: 3.8803x; 1.0644x over previous
//
#include <hip/hip_runtime.h>

#define EPS 1e-5f

typedef __attribute__((ext_vector_type(8))) short s8v;   // 8 x bf16 bits
typedef __attribute__((ext_vector_type(4))) float f4v;   // MFMA accumulator

__device__ __forceinline__ unsigned short f2b(float x) {
  unsigned int u = __float_as_uint(x);
  u += 0x7FFFu + ((u >> 16) & 1u);
  return (unsigned short)(u >> 16);
}
__device__ __forceinline__ float b2f(unsigned short b) {
  return __uint_as_float(((unsigned int)b) << 16);
}

// ---------------------------------------------------------------------------
// Split-K GEMM, BK=64, tile 256x64, bf16 partials. Kernel boundary = sync.
//   A: 256 x K bf16 (lda mult of 64-friendly: host guarantees every staged
//      64-col slab [kb, kb+64) satisfies kb+64 <= lda, pads zero)
//   B: N x K f32 row-major.
//   4 waves; wave w owns rows w*64..w*64+63 (fm=4). 32 MFMA per barrier pair.
//   bid: ky = bid % KS, ntp = bid / KS. Partial tile (256x64 bf16, 32KB):
//   Pb[(ky*NPAIR + ntp)*16384 + row*64 + col].
//   HOST INVARIANT: kchunk % 64 == 0 (round-4 lesson, now at 64 granularity).
// ---------------------------------------------------------------------------
__global__ __launch_bounds__(256)
void gemm_bk64(const unsigned short* __restrict__ A, int lda,
               const float* __restrict__ B, int ldb,
               unsigned short* __restrict__ Pb,
               int NPAIR, int N, int K, int kchunk, int KS)
{
  __shared__ unsigned short As[256 * 72];
  __shared__ unsigned short Bs[64 * 72];
  const int bid = (int)blockIdx.x;
  const int ky = bid % KS, ntp = bid / KS;
  const int n0 = ntp << 6;
  const int t = threadIdx.x, lane = t & 63, w = t >> 6;
  const int lr = lane & 15, lk = lane >> 4;

  const int kstart = ky * kchunk;
  const int kend = min(K, kstart + kchunk);
  const int len = kend - kstart;
  const int nfull = len >> 6;
  const int rem = len & 63;

  const int ar = t >> 2, ac = t & 3;     // A: rows ar + p*64, 16-col half ac
  const int br = t >> 2, bq = t & 3;     // B: row br (0..63), 16-col quad bq

  f4v acc[4][4] = {};
  float4 b_cur[4], b_nxt[4];

  auto loadB = [&](float4* dst, int kb) {
    const int row = n0 + br;
    if (row < N) {
      #pragma unroll
      for (int i = 0; i < 4; ++i)
        dst[i] = *(const float4*)(B + (size_t)row * ldb + kb + bq * 16 + i * 4);
    } else {
      #pragma unroll
      for (int i = 0; i < 4; ++i) { dst[i].x = dst[i].y = dst[i].z = dst[i].w = 0.f; }
    }
  };
  auto stageA = [&](int kb) {            // A loaded just-in-time (L2/L3-resident)
    #pragma unroll
    for (int p = 0; p < 4; ++p) {
      const int row = ar + p * 64;
      const s8v v0 = *(const s8v*)(A + (size_t)row * lda + kb + ac * 16);
      const s8v v1 = *(const s8v*)(A + (size_t)row * lda + kb + ac * 16 + 8);
      *(s8v*)(As + row * 72 + ac * 16) = v0;
      *(s8v*)(As + row * 72 + ac * 16 + 8) = v1;
    }
  };
  auto stageB = [&](const float4* bv) {
    s8v p0, p1;
    #pragma unroll
    for (int i = 0; i < 4; ++i) {
      p0[i]     = (short)f2b(bv[i >> 1].x); // careful packing below instead
    }
    // pack 16 f32 -> 16 bf16 (two s8v)
    p0[0] = (short)f2b(bv[0].x); p0[1] = (short)f2b(bv[0].y);
    p0[2] = (short)f2b(bv[0].z); p0[3] = (short)f2b(bv[0].w);
    p0[4] = (short)f2b(bv[1].x); p0[5] = (short)f2b(bv[1].y);
    p0[6] = (short)f2b(bv[1].z); p0[7] = (short)f2b(bv[1].w);
    p1[0] = (short)f2b(bv[2].x); p1[1] = (short)f2b(bv[2].y);
    p1[2] = (short)f2b(bv[2].z); p1[3] = (short)f2b(bv[2].w);
    p1[4] = (short)f2b(bv[3].x); p1[5] = (short)f2b(bv[3].y);
    p1[6] = (short)f2b(bv[3].z); p1[7] = (short)f2b(bv[3].w);
    *(s8v*)(Bs + br * 72 + bq * 16) = p0;
    *(s8v*)(Bs + br * 72 + bq * 16 + 8) = p1;
  };
  auto domfma = [&]() {
    #pragma unroll
    for (int ks = 0; ks < 2; ++ks) {
      s8v af[4], bf[4];
      #pragma unroll
      for (int fm = 0; fm < 4; ++fm)
        af[fm] = *(const s8v*)(As + (w * 64 + fm * 16 + lr) * 72 + ks * 32 + lk * 8);
      #pragma unroll
      for (int fn = 0; fn < 4; ++fn)
        bf[fn] = *(const s8v*)(Bs + (fn * 16 + lr) * 72 + ks * 32 + lk * 8);
      #pragma unroll
      for (int fm = 0; fm < 4; ++fm)
        #pragma unroll
        for (int fn = 0; fn < 4; ++fn)
          acc[fm][fn] = __builtin_amdgcn_mfma_f32_16x16x32_bf16(af[fm], bf[fn], acc[fm][fn], 0, 0, 0);
    }
  };

  int kb = kstart;
  if (nfull > 0) {
    loadB(b_cur, kb);
    for (int s = 0; s < nfull; ++s) {
      stageA(kb);
      stageB(b_cur);
      __syncthreads();
      const bool more = (s + 1 < nfull);
      if (more) loadB(b_nxt, kb + 64);
      domfma();
      __syncthreads();
      if (more) {
        #pragma unroll
        for (int i = 0; i < 4; ++i) b_cur[i] = b_nxt[i];
        kb += 64;
      }
    }
    kb += 64;
  }
  if (rem) {
    // Last chunk only (kchunk % 64 == 0). A: kb+64 <= lda by host invariant,
    // pads zero. B: guarded per element by kend; out-of-range -> 0.
    stageA(kb);
    {
      const int row = n0 + br;
      #pragma unroll
      for (int i = 0; i < 4; ++i) {
        float e[4];
        #pragma unroll
        for (int v = 0; v < 4; ++v) {
          const int c = kb + bq * 16 + i * 4 + v;
          e[v] = (row < N && c < kend) ? B[(size_t)row * ldb + c] : 0.f;
        }
        b_cur[i].x = e[0]; b_cur[i].y = e[1]; b_cur[i].z = e[2]; b_cur[i].w = e[3];
      }
    }
    stageB(b_cur);
    __syncthreads();
    domfma();
    __syncthreads();
  }

  unsigned short* Pt = Pb + ((size_t)ky * NPAIR + ntp) * 16384;
  #pragma unroll
  for (int fm = 0; fm < 4; ++fm)
    #pragma unroll
    for (int fn = 0; fn < 4; ++fn) {
      const int col = fn * 16 + lr;
      #pragma unroll
      for (int j = 0; j < 4; ++j) {
        const int row = w * 64 + fm * 16 + lk * 4 + j;
        Pt[row * 64 + col] = f2b(acc[fm][fn][j]);
      }
    }
}

// ---------------------------------------------------------------------------
// Reduce bf16 partials (f32 accumulate) + epilogue.
// Grid = NPAIR*4; block (ntp, qr) covers rows qr*64..+64 of the 64-col panel.
// Thread: row = qr*64 + t/4, cols (t&3)*16..+16.
// ---------------------------------------------------------------------------
template<bool BN, bool RES, bool WRD, bool WRT, bool F32OUT>
__global__ __launch_bounds__(256)
void reduce_bk64(const unsigned short* __restrict__ Pb, int KS, int NPAIR, int N,
                 const float* __restrict__ bias,
                 const float* __restrict__ g, const float* __restrict__ bb,
                 const float* __restrict__ rm, const float* __restrict__ rv,
                 float* __restrict__ dR, int lddr,
                 unsigned short* __restrict__ Cb, int ldc,
                 unsigned short* __restrict__ Ct, float* __restrict__ Cf)
{
  const int bid = (int)blockIdx.x;
  const int ntp = bid >> 2, qr = bid & 3;
  const int t = threadIdx.x;
  const int row = qr * 64 + (t >> 2);
  const int c0 = (t & 3) * 16;
  const int n0 = ntp << 6;

  float vv[16];
  #pragma unroll
  for (int e = 0; e < 16; ++e) vv[e] = 0.f;

  const unsigned short* base = Pb + (size_t)ntp * 16384 + row * 64 + c0;
  for (int ky = 0; ky < KS; ++ky) {
    const s8v pa = *(const s8v*)(base + (size_t)ky * NPAIR * 16384);
    const s8v pb2 = *(const s8v*)(base + (size_t)ky * NPAIR * 16384 + 8);
    #pragma unroll
    for (int e = 0; e < 8; ++e) vv[e]     += b2f((unsigned short)pa[e]);
    #pragma unroll
    for (int e = 0; e < 8; ++e) vv[8 + e] += b2f((unsigned short)pb2[e]);
  }

  unsigned short outp[16];
  #pragma unroll
  for (int e = 0; e < 16; ++e) {
    const int col = n0 + c0 + e;
    float v = 0.f;
    if (col < N) {
      v = vv[e] + bias[col];
      if (BN) { const float s = g[col] * rsqrtf(rv[col] + EPS); v = (v - rm[col]) * s + bb[col]; }
      v = fmaxf(v, 0.f);
      if (RES) v += dR[(size_t)row * lddr + col];
      if (WRD) dR[(size_t)row * lddr + col] = v;
      if (F32OUT) Cf[(size_t)row * N + col] = v;
      else if (WRT) Ct[(size_t)col * 256 + row] = f2b(v);
    }
    outp[e] = f2b(v);
  }
  if (!F32OUT && !WRT) {
    *(s8v*)(Cb + (size_t)row * ldc + n0 + c0) = *(const s8v*)(outp);
    *(s8v*)(Cb + (size_t)row * ldc + n0 + c0 + 8) = *(const s8v*)(outp + 8);
  }
}

// ---------------------------------------------------------------------------
// Prep: pack x-geno to bf16, pack env rows, zero h5b pads (stride 13376).
// ---------------------------------------------------------------------------
__global__ __launch_bounds__(256)
void prep_k(const float* __restrict__ x, unsigned short* __restrict__ xg,
            unsigned short* __restrict__ envb, unsigned short* __restrict__ h5b)
{
  const int bid = (int)blockIdx.x, t = threadIdx.x;
  if (bid < 16384) {
    const int idx = bid * 256 + t;
    const int r = idx >> 14, c = idx & 16383;
    xg[idx] = f2b(x[(size_t)r * 16437 + c]);
  } else if (bid < 16456) {
    const int idx = (bid - 16384) * 256 + t;
    const int b = idx / 72, c = idx % 72;
    envb[idx] = (c < 53) ? f2b(x[(size_t)b * 16437 + 16384 + c]) : (unsigned short)0;
  } else {
    for (int z = t; z < 256 * 46; z += 256) {
      const int b = z / 46, j = z % 46;
      h5b[(size_t)b * 13376 + 13330 + j] = 0;
    }
  }
}

// ---------------------------------------------------------------------------
// Fused head: per unit i, 4 chained 256x64x64 GEMMs in LDS/regs.
// (unchanged except h5b stride 13376)
// ---------------------------------------------------------------------------
__global__ __launch_bounds__(256, 2)
void fused_head(const unsigned short* __restrict__ envb,
                const unsigned short* __restrict__ htr,
                const float* __restrict__ Wlin, const float* __restrict__ blin,
                const float* __restrict__ W13, const float* __restrict__ b13,
                const float* __restrict__ W14, const float* __restrict__ b14,
                const float* __restrict__ W15, const float* __restrict__ b15,
                const float* __restrict__ bn3g, const float* __restrict__ bn3b,
                const float* __restrict__ bn3rm, const float* __restrict__ bn3rv,
                unsigned short* __restrict__ h5b)
{
  __shared__ unsigned short act[256 * 72];
  __shared__ unsigned short Wl[64 * 72];
  __shared__ unsigned short Wa[64 * 72];
  __shared__ unsigned short Wb[16 * 72];
  const int i = (int)blockIdx.x;
  const int t = threadIdx.x, lane = t & 63, w = t >> 6;
  const int lr = lane & 15, lk = lane >> 4;
  const int R = 2666;

  #pragma unroll
  for (int c8 = 0; c8 < 9; ++c8)
    *(s8v*)(act + t * 72 + c8 * 8) = *(const s8v*)(envb + t * 72 + c8 * 8);
  act[t * 72 + 53] = htr[(size_t)i * 256 + t];

  const float* wli = Wlin + (size_t)i * 2916;
  for (int idx = t; idx < 64 * 72; idx += 256) {
    const int r = idx / 72, f = idx % 72;
    Wl[idx] = (r < 54 && f < 54) ? f2b(wli[r * 54 + f]) : (unsigned short)0;
    Wa[idx] = (r < 54 && f < 54) ? f2b(W13[r * 54 + f]) : (unsigned short)0;
  }
  for (int idx = t; idx < 16 * 72; idx += 256) {
    const int r = idx / 72, f = idx % 72;
    Wb[idx] = (r < 5 && f < 54) ? f2b(W15[r * 54 + f]) : (unsigned short)0;
  }
  const float s0 = bn3g[i] * rsqrtf(bn3rv[i] + EPS), m0 = bn3rm[i], c0 = bn3b[i];
  const float s1 = bn3g[R+i] * rsqrtf(bn3rv[R+i] + EPS), m1 = bn3rm[R+i], c1 = bn3b[R+i];
  const float s2 = bn3g[2*R+i] * rsqrtf(bn3rv[2*R+i] + EPS), m2 = bn3rm[2*R+i], c2 = bn3b[2*R+i];
  __syncthreads();

  const int abase = (w * 64 + lr) * 72 + lk * 8;
  f4v acc[4][4];

  auto zacc = [&]() {
    #pragma unroll
    for (int a = 0; a < 4; ++a)
      #pragma unroll
      for (int b = 0; b < 4; ++b) acc[a][b] = f4v{0.f, 0.f, 0.f, 0.f};
  };
  auto gemm4 = [&](const unsigned short* B) {
    s8v af[2][4];
    #pragma unroll
    for (int ks = 0; ks < 2; ++ks)
      #pragma unroll
      for (int fm = 0; fm < 4; ++fm)
        af[ks][fm] = *(const s8v*)(act + abase + fm * 16 * 72 + ks * 32);
    #pragma unroll
    for (int fn = 0; fn < 4; ++fn) {
      s8v b0 = *(const s8v*)(B + (fn * 16 + lr) * 72 + lk * 8);
      s8v b1 = *(const s8v*)(B + (fn * 16 + lr) * 72 + 32 + lk * 8);
      #pragma unroll
      for (int fm = 0; fm < 4; ++fm) {
        acc[fm][fn] = __builtin_amdgcn_mfma_f32_16x16x32_bf16(af[0][fm], b0, acc[fm][fn], 0, 0, 0);
        acc[fm][fn] = __builtin_amdgcn_mfma_f32_16x16x32_bf16(af[1][fm], b1, acc[fm][fn], 0, 0, 0);
      }
    }
  };
  auto epi_bn = [&](const float* bias, float s, float m, float c) {
    #pragma unroll
    for (int fn = 0; fn < 4; ++fn) {
      const int o = fn * 16 + lr;
      const float bo = (o < 54) ? bias[o] : 0.f;
      #pragma unroll
      for (int fm = 0; fm < 4; ++fm)
        #pragma unroll
        for (int j = 0; j < 4; ++j) {
          const int row = w * 64 + fm * 16 + lk * 4 + j;
          float v = acc[fm][fn][j] + bo;
          v = (v - m) * s + c;
          v = fmaxf(v, 0.f);
          act[row * 72 + o] = (o < 54) ? f2b(v) : (unsigned short)0;
        }
    }
  };

  zacc(); gemm4(Wl);
  #pragma unroll
  for (int fn = 0; fn < 4; ++fn) {
    const int o = fn * 16 + lr;
    const float bl = (o < 54) ? blin[(size_t)i * 54 + o] : 0.f;
    #pragma unroll
    for (int fm = 0; fm < 4; ++fm)
      #pragma unroll
      for (int j = 0; j < 4; ++j) {
        const int row = w * 64 + fm * 16 + lk * 4 + j;
        float v = acc[fm][fn][j] + bl;
        act[row * 72 + o] = (o < 54) ? f2b(v) : (unsigned short)0;
      }
  }
  __syncthreads();
  for (int idx = t; idx < 64 * 72; idx += 256) {
    const int r = idx / 72, f = idx % 72;
    Wl[idx] = (r < 54 && f < 54) ? f2b(W14[r * 54 + f]) : (unsigned short)0;
  }
  zacc(); gemm4(Wa); epi_bn(b13, s0, m0, c0);
  __syncthreads();
  zacc(); gemm4(Wl); epi_bn(b14, s1, m1, c1);
  f4v a4[4] = {};
  {
    s8v af[2][4];
    #pragma unroll
    for (int ks = 0; ks < 2; ++ks)
      #pragma unroll
      for (int fm = 0; fm < 4; ++fm)
        af[ks][fm] = *(const s8v*)(act + abase + fm * 16 * 72 + ks * 32);
    s8v b0 = *(const s8v*)(Wb + lr * 72 + lk * 8);
    s8v b1 = *(const s8v*)(Wb + lr * 72 + 32 + lk * 8);
    #pragma unroll
    for (int fm = 0; fm < 4; ++fm) {
      a4[fm] = __builtin_amdgcn_mfma_f32_16x16x32_bf16(af[0][fm], b0, a4[fm], 0, 0, 0);
      a4[fm] = __builtin_amdgcn_mfma_f32_16x16x32_bf16(af[1][fm], b1, a4[fm], 0, 0, 0);
    }
  }
  if (lr < 5) {
    const float b5 = b15[lr];
    #pragma unroll
    for (int fm = 0; fm < 4; ++fm)
      #pragma unroll
      for (int j = 0; j < 4; ++j) {
        const int row = w * 64 + fm * 16 + lk * 4 + j;
        float v = a4[fm][j] + b5;
        v = (v - m2) * s2 + c2;
        v = fmaxf(v, 0.f);
        h5b[(size_t)row * 13376 + (size_t)i * 5 + lr] = f2b(v);
      }
  }
}

extern "C" void kernel_launch(void* const* d_in, const int* in_sizes, int n_in,
                              void* d_out, int out_size, void* d_ws, size_t ws_size,
                              hipStream_t stream)
{
  const float* x    = (const float*)d_in[0];
  const float* W1   = (const float*)d_in[1];
  const float* b1   = (const float*)d_in[2];
  const float* Wmid = (const float*)d_in[3];
  const float* bmid = (const float*)d_in[4];
  const float* bng  = (const float*)d_in[5];
  const float* bnb  = (const float*)d_in[6];
  const float* bnrm = (const float*)d_in[7];
  const float* bnrv = (const float*)d_in[8];
  const float* Wlin = (const float*)d_in[9];
  const float* blin = (const float*)d_in[10];
  const float* W13  = (const float*)d_in[11];
  const float* b13  = (const float*)d_in[12];
  const float* W14  = (const float*)d_in[13];
  const float* b14  = (const float*)d_in[14];
  const float* W15  = (const float*)d_in[15];
  const float* b15  = (const float*)d_in[16];
  const float* bn3g = (const float*)d_in[17];
  const float* bn3b = (const float*)d_in[18];
  const float* bn3rm= (const float*)d_in[19];
  const float* bn3rv= (const float*)d_in[20];
  const float* W16  = (const float*)d_in[21];
  const float* b16  = (const float*)d_in[22];
  const float* W17  = (const float*)d_in[23];
  const float* b17  = (const float*)d_in[24];
  const float* W18  = (const float*)d_in[25];
  const float* b18  = (const float*)d_in[26];

  const int R = 2666;
  char* p = (char*)d_ws;
  unsigned short* xg  = (unsigned short*)p; p += (size_t)256 * 16384 * 2;
  unsigned short* hA  = (unsigned short*)p; p += (size_t)256 * 2688 * 2;
  unsigned short* hB  = (unsigned short*)p; p += (size_t)256 * 2688 * 2;
  float*          dR  = (float*)p;          p += (size_t)256 * 2688 * 4;
  unsigned short* h5b = (unsigned short*)p; p += (size_t)256 * 13376 * 2;
  unsigned short* h6b = (unsigned short*)p; p += (size_t)256 * 768 * 2;
  unsigned short* h7b = (unsigned short*)p; p += (size_t)256 * 768 * 2;
  unsigned short* envb= (unsigned short*)p; p += (size_t)256 * 72 * 2;
  unsigned short* htr = (unsigned short*)p; p += (size_t)2666 * 256 * 2;
  unsigned short* Pb  = (unsigned short*)p; // bf16 partials, <= 18.4 MB

  dim3 TB(256);

  prep_k<<<dim3(16457), TB, 0, stream>>>(x, xg, envb, h5b);

  // L1: K=16384, NPAIR=42, KS=8, kchunk=2048 (32 steps, rem=0). Grid 336.
  gemm_bk64<<<dim3(42 * 8), TB, 0, stream>>>(xg, 16384, W1, 16384, Pb, 42, R, 16384, 2048, 8);
  reduce_bk64<true, false, true, false, false><<<dim3(42 * 4), TB, 0, stream>>>(
      Pb, 8, 42, R, b1, bng, bnb, bnrm, bnrv, dR, 2688, hA, 2688, nullptr, nullptr);

  // mids: K=2666, NPAIR=42, KS=14, kchunk=192 (3 steps; ky=13: 2496..2666,
  // nfull=2, rem=42 -> staged slab 2624..2688 = lda). Grid 588.
  unsigned short* cur = hA; unsigned short* nxt = hB;
  for (int k = 0; k < 11; ++k) {
    const float* bw = Wmid + (size_t)k * R * R;
    const float* bs = bmid + (size_t)k * R;
    const int L = k + 1;
    gemm_bk64<<<dim3(42 * 14), TB, 0, stream>>>(cur, 2688, bw, R, Pb, 42, R, R, 192, 14);
    if (k == 10)
      reduce_bk64<true, false, false, true, false><<<dim3(42 * 4), TB, 0, stream>>>(
          Pb, 14, 42, R, bs, bng + (size_t)L * R, bnb + (size_t)L * R,
          bnrm + (size_t)L * R, bnrv + (size_t)L * R,
          nullptr, 0, nullptr, 2688, htr, nullptr);
    else if ((k & 1) == 0)
      reduce_bk64<true, false, false, false, false><<<dim3(42 * 4), TB, 0, stream>>>(
          Pb, 14, 42, R, bs, bng + (size_t)L * R, bnb + (size_t)L * R,
          bnrm + (size_t)L * R, bnrv + (size_t)L * R,
          nullptr, 0, nxt, 2688, nullptr, nullptr);
    else
      reduce_bk64<true, true, true, false, false><<<dim3(42 * 4), TB, 0, stream>>>(
          Pb, 14, 42, R, bs, bng + (size_t)L * R, bnb + (size_t)L * R,
          bnrm + (size_t)L * R, bnrv + (size_t)L * R,
          dR, 2688, nxt, 2688, nullptr, nullptr);
    unsigned short* tmp = cur; cur = nxt; nxt = tmp;
  }

  // Fused d3 -> W13 -> W14 -> W15 chain
  fused_head<<<dim3(2666), TB, 0, stream>>>(
      envb, htr, Wlin, blin, W13, b13, W14, b14, W15, b15,
      bn3g, bn3b, bn3rm, bn3rv, h5b);

  // W16: K=13330, NPAIR=12, KS=15, kchunk=896 (ky=14: 12544..13330, nfull=12,
  // rem=18 -> staged slab 13312..13376 = lda 13376). Grid 180.
  gemm_bk64<<<dim3(12 * 15), TB, 0, stream>>>(h5b, 13376, W16, 13330, Pb, 12, 750, 13330, 896, 15);
  reduce_bk64<false, false, false, false, false><<<dim3(12 * 4), TB, 0, stream>>>(
      Pb, 15, 12, 750, b16, nullptr, nullptr, nullptr, nullptr,
      nullptr, 0, h6b, 768, nullptr, nullptr);

  // W17: K=750, NPAIR=12, KS=6, kchunk=128 (ky=5: 640..750, nfull=1, rem=46
  // -> staged slab 704..768 = lda). Grid 72.
  gemm_bk64<<<dim3(12 * 6), TB, 0, stream>>>(h6b, 768, W17, 750, Pb, 12, 750, 750, 128, 6);
  reduce_bk64<false, false, false, false, false><<<dim3(12 * 4), TB, 0, stream>>>(
      Pb, 6, 12, 750, b17, nullptr, nullptr, nullptr, nullptr,
      nullptr, 0, h7b, 768, nullptr, nullptr);

  // W18 -> f32 d_out
  gemm_bk64<<<dim3(12 * 6), TB, 0, stream>>>(h7b, 768, W18, 750, Pb, 12, 750, 750, 128, 6);
  reduce_bk64<false, false, false, false, true><<<dim3(12 * 4), TB, 0, stream>>>(
      Pb, 6, 12, 750, b18, nullptr, nullptr, nullptr, nullptr,
      nullptr, 0, nullptr, 768, nullptr, (float*)d_out);
}